// Round 3
// baseline (7257.244 us; speedup 1.0000x reference)
//
#include <hip/hip_runtime.h>
#include <stdint.h>

#define NTOK 10992      // B*SN
#define NTOKA 11264     // padded token dim (8*1408 = 88*128)
#define CHK 1408        // backward token chunk (11*128)
#define NCH 8
#define CHK2 2816       // final-forward chunk (22*128)
#define NCH2 4

typedef unsigned short u16;
typedef __attribute__((ext_vector_type(8))) __bf16 b8;
typedef __attribute__((ext_vector_type(4))) float f32x4;

__device__ __forceinline__ u16 f2b(float f) {
  union { float f; uint32_t u; } v; v.f = f;
  return (u16)((v.u + 0x7fffu + ((v.u >> 16) & 1u)) >> 16);   // RNE
}
__device__ __forceinline__ float b2f(u16 b) {
  union { uint32_t u; float f; } v; v.u = ((uint32_t)b) << 16; return v.f;
}

__device__ __forceinline__ void gload16(const u16* g, u16* l) {
  __builtin_amdgcn_global_load_lds((const __attribute__((address_space(1))) void*)(const void*)g,
                                   (__attribute__((address_space(3))) void*)(void*)l, 16, 0, 0);
}

struct GA {
  const u16* A[3]; const u16* B[3];
  void* C[3]; u16* O1[3];
  const void* E0[3]; const u16* E1[3];
  int lda[3], ldb[3];
  int M, K, ldc, ldo1, lde0, lde1;
  float p0, p1;
};

// C[m,n] = sum_k A[m,k]*B[n,k]  (both operands k-contig bf16)
// EPI: 0 none | 1 +E0f[n] fp32 bias | 2 (acc-b2f(E0b[m,n]))*p0 | 3 C=acc, O1=swish(E0b)*acc
//      4 C=swish(E0b)*acc | 5 dual in-place dzg/dzv | 7 p0*b2f(E0b[m,n])+p1*acc | 8 Cf += acc
template <int EPI, int CB>
__global__ __launch_bounds__(256, 2) void gemm_bt(GA g) {
  __shared__ u16 As[128 * 32];
  __shared__ u16 Bs[128 * 32];
  const int bz = blockIdx.z;
  const u16* __restrict__ A = g.A[bz];
  const u16* __restrict__ B = g.B[bz];
  const int lda = g.lda[bz], ldb = g.ldb[bz];
  const int m0 = blockIdx.y * 128, n0 = blockIdx.x * 128;
  const int tid = threadIdx.x, w = tid >> 6, lane = tid & 63;
  const int wr = (w >> 1) * 64, wc = (w & 1) * 64;
  const int ln = lane & 15, lq = lane >> 4;

  f32x4 acc[4][4];
#pragma unroll
  for (int i = 0; i < 4; ++i)
#pragma unroll
    for (int j = 0; j < 4; ++j)
#pragma unroll
      for (int r = 0; r < 4; ++r) acc[i][j][r] = 0.f;

  const u16* Ag = A + (size_t)(m0 + 32 * w + (lane >> 2)) * lda + (lane & 3) * 8;
  const u16* Bg = B + (size_t)(n0 + 32 * w + (lane >> 2)) * ldb + (lane & 3) * 8;
  u16* AsW = &As[w * 1024];
  u16* BsW = &Bs[w * 1024];
  const int nkt = g.K >> 5;

  for (int kt = 0; kt < nkt; ++kt) {
    __syncthreads();
    gload16(Ag, AsW);
    gload16(Ag + (size_t)16 * lda, AsW + 512);
    gload16(Bg, BsW);
    gload16(Bg + (size_t)16 * ldb, BsW + 512);
    Ag += 32; Bg += 32;
    __syncthreads();
    b8 af[4], bfr[4];
#pragma unroll
    for (int i = 0; i < 4; ++i) af[i] = *(const b8*)&As[(wr + i * 16 + ln) * 32 + lq * 8];
#pragma unroll
    for (int j = 0; j < 4; ++j) bfr[j] = *(const b8*)&Bs[(wc + j * 16 + ln) * 32 + lq * 8];
#pragma unroll
    for (int i = 0; i < 4; ++i)
#pragma unroll
      for (int j = 0; j < 4; ++j)
        acc[i][j] = __builtin_amdgcn_mfma_f32_16x16x32_bf16(af[i], bfr[j], acc[i][j], 0, 0, 0);
  }

  float* Cf = (float*)g.C[bz];
  u16* Cb = (u16*)g.C[bz];
  u16* O1 = g.O1[bz];
  const float* E0f = (const float*)g.E0[bz];
  const u16* E0b = (const u16*)g.E0[bz];
  const u16* E1b = g.E1[bz];

#pragma unroll
  for (int i = 0; i < 4; ++i) {
#pragma unroll
    for (int r = 0; r < 4; ++r) {
      const int m = m0 + wr + i * 16 + lq * 4 + r;
      if (m >= g.M) continue;
#pragma unroll
      for (int j = 0; j < 4; ++j) {
        const int n = n0 + wc + j * 16 + ln;
        float v = acc[i][j][r];
        const size_t ci = (size_t)m * g.ldc + n;
        if constexpr (EPI == 1) {
          v += E0f[n];
        } else if constexpr (EPI == 2) {
          v = (v - b2f(E0b[(size_t)m * g.lde0 + n])) * g.p0;
        } else if constexpr (EPI == 3) {
          float zg = b2f(E0b[(size_t)m * g.lde0 + n]);
          float s = 1.f / (1.f + __expf(-zg));
          O1[(size_t)m * g.ldo1 + n] = f2b(zg * s * v);
        } else if constexpr (EPI == 4) {
          float zg = b2f(E0b[(size_t)m * g.lde0 + n]);
          float s = 1.f / (1.f + __expf(-zg));
          v = zg * s * v;
        } else if constexpr (EPI == 5) {
          float zg = b2f(E0b[(size_t)m * g.lde0 + n]);
          float zv = b2f(E1b[(size_t)m * g.lde1 + n]);
          float s = 1.f / (1.f + __expf(-zg));
          Cb[ci] = f2b(v * zv * s * (1.f + zg * (1.f - s)));   // dzg over zg
          O1[(size_t)m * g.ldo1 + n] = f2b(v * zg * s);        // dzv over zv
        } else if constexpr (EPI == 7) {
          v = g.p0 * b2f(E0b[(size_t)m * g.lde0 + n]) + g.p1 * v;
        }
        if constexpr (EPI == 5) {
        } else if constexpr (EPI == 8) {
          Cf[ci] += v;
        } else {
          if constexpr (CB) Cb[ci] = f2b(v); else Cf[ci] = v;
        }
      }
    }
  }
}

// bf16 qkv row -> per-head L2 norm + affine -> qb,kb ; copies v -> vb. one block per token.
__global__ __launch_bounds__(256) void norm_qkv(const u16* __restrict__ qkvB,
    const float* __restrict__ qs, const float* __restrict__ qbi,
    const float* __restrict__ ks, const float* __restrict__ kbi,
    u16* __restrict__ qb, u16* __restrict__ kb, u16* __restrict__ vb) {
  const int tok = blockIdx.x;
  const int t = threadIdx.x;
  const int d = t * 4;
  const u16* row = qkvB + (size_t)tok * 3072;
  const uint2 qu = *(const uint2*)(row + d);
  const uint2 ku = *(const uint2*)(row + 1024 + d);
  *(uint2*)(vb + (size_t)tok * 1024 + d) = *(const uint2*)(row + 2048 + d);
  float q0 = b2f(qu.x & 0xffff), q1 = b2f(qu.x >> 16), q2 = b2f(qu.y & 0xffff), q3 = b2f(qu.y >> 16);
  float k0 = b2f(ku.x & 0xffff), k1 = b2f(ku.x >> 16), k2 = b2f(ku.y & 0xffff), k3 = b2f(ku.y >> 16);
  float sq = q0 * q0 + q1 * q1 + q2 * q2 + q3 * q3;
  float sk = k0 * k0 + k1 * k1 + k2 * k2 + k3 * k3;
  for (int off = 1; off < 16; off <<= 1) { sq += __shfl_xor(sq, off); sk += __shfl_xor(sk, off); }
  const float rq = 1.f / (sqrtf(sq) + 1e-6f);
  const float rk = 1.f / (sqrtf(sk) + 1e-6f);
  const int hd = d & 63;
  const float4 qsv = *(const float4*)(qs + hd);
  const float4 qbv = *(const float4*)(qbi + hd);
  const float4 ksv = *(const float4*)(ks + hd);
  const float4 kbv = *(const float4*)(kbi + hd);
  uint64_t pq = (uint64_t)f2b(q0 * rq * qsv.x + qbv.x)
              | ((uint64_t)f2b(q1 * rq * qsv.y + qbv.y) << 16)
              | ((uint64_t)f2b(q2 * rq * qsv.z + qbv.z) << 32)
              | ((uint64_t)f2b(q3 * rq * qsv.w + qbv.w) << 48);
  uint64_t pk = (uint64_t)f2b(k0 * rk * ksv.x + kbv.x)
              | ((uint64_t)f2b(k1 * rk * ksv.y + kbv.y) << 16)
              | ((uint64_t)f2b(k2 * rk * ksv.z + kbv.z) << 32)
              | ((uint64_t)f2b(k3 * rk * ksv.w + kbv.w) << 48);
  *(uint64_t*)(qb + (size_t)tok * 1024 + d) = pq;
  *(uint64_t*)(kb + (size_t)tok * 1024 + d) = pk;
}

// bf16 transpose: in [*, Cin] -> out [Cin, Rtot]; rows >= Rval read as 0
__global__ __launch_bounds__(256) void tr_b16(const u16* __restrict__ in, u16* __restrict__ out,
                                              int Cin, int Rtot, int Rval,
                                              size_t inStr, size_t outStr) {
  const int b = blockIdx.z;
  in += (size_t)b * inStr; out += (size_t)b * outStr;
  __shared__ u16 t[32][33];
  const int c0 = blockIdx.x * 32, r0 = blockIdx.y * 32;
  const int tx = threadIdx.x, ty = threadIdx.y;
#pragma unroll
  for (int yy = 0; yy < 4; ++yy) {
    const int rr = ty * 4 + yy;
    const int r = r0 + rr;
    t[rr][tx] = (r < Rval) ? in[(size_t)r * Cin + c0 + tx] : (u16)0;
  }
  __syncthreads();
#pragma unroll
  for (int yy = 0; yy < 4; ++yy) {
    const int cc = ty * 4 + yy;
    out[(size_t)(c0 + cc) * Rtot + r0 + tx] = t[tx][cc];
  }
}

// fp32 -> transposed bf16: in [Rtot, Cin] f32 -> out [Cin, Rtot] bf16
__global__ __launch_bounds__(256) void tr_f32b(const float* __restrict__ in, u16* __restrict__ out,
                                               int Cin, int Rtot) {
  __shared__ u16 t[32][33];
  const int c0 = blockIdx.x * 32, r0 = blockIdx.y * 32;
  const int tx = threadIdx.x, ty = threadIdx.y;
#pragma unroll
  for (int yy = 0; yy < 4; ++yy) {
    const int rr = ty * 4 + yy;
    t[rr][tx] = f2b(in[(size_t)(r0 + rr) * Cin + c0 + tx]);
  }
  __syncthreads();
#pragma unroll
  for (int yy = 0; yy < 4; ++yy) {
    const int cc = ty * 4 + yy;
    out[(size_t)(c0 + cc) * Rtot + r0 + tx] = t[tx][cc];
  }
}

__global__ void cvt_k(const float* __restrict__ in, u16* __restrict__ out, int n) {
  const int i = blockIdx.x * 256 + threadIdx.x;
  if (i < n) out[i] = f2b(in[i]);
}

__global__ void diag_k(float* __restrict__ out, int n, float val) {
  const int i = blockIdx.x * 256 + threadIdx.x;
  if (i < n) out[i] = val;
}

__global__ __launch_bounds__(256) void sumsq_k(const float* __restrict__ g, float* __restrict__ out) {
  const int b = blockIdx.y;
  const float* p = g + (size_t)b * 4194304;
  float s = 0.f;
  for (int i = blockIdx.x * 256 + threadIdx.x; i < 4194304; i += gridDim.x * 256) {
    float v = p[i]; s += v * v;
  }
  for (int off = 32; off > 0; off >>= 1) s += __shfl_xor(s, off);
  __shared__ float red[4];
  if ((threadIdx.x & 63) == 0) red[threadIdx.x >> 6] = s;
  __syncthreads();
  if (threadIdx.x == 0) atomicAdd(out + b, red[0] + red[1] + red[2] + red[3]);
}

__global__ __launch_bounds__(256) void scale_k(const float* __restrict__ g, const float* __restrict__ ss,
                                               u16* __restrict__ Xb) {
  const int b = blockIdx.y;
  const float r = 1.f / (sqrtf(ss[b]) + 1e-7f);
  const size_t o = (size_t)b * 4194304;
  for (int i = blockIdx.x * 256 + threadIdx.x; i < 4194304; i += gridDim.x * 256)
    Xb[o + i] = f2b(g[o + i] * r);
}

// theta(bf16 masters) -= 0.1*X.  X: [1024(d), 4096(j)] bf16 per param (stride 4M).
// b=0: Gt[j,d] -= .1*X[d,j]; b=1: Vt; b=2: nv = Pb[j,d]-.1*X[d,j]; Pb[j,d]=nv; Pt[d,j]=nv.
__global__ __launch_bounds__(256) void muon_apply(const u16* __restrict__ Xb_,
    u16* __restrict__ Gt, u16* __restrict__ Vt, u16* __restrict__ Pt, u16* __restrict__ Pb) {
  const int b = blockIdx.z;
  __shared__ float xs[32][33];
  __shared__ u16 ns[32][33];
  const int j0 = blockIdx.x * 32;  // 4096-dim
  const int i0 = blockIdx.y * 32;  // 1024-dim
  const u16* X = Xb_ + (size_t)b * 4194304;
  const int tx = threadIdx.x, ty = threadIdx.y;
#pragma unroll
  for (int yy = 0; yy < 4; ++yy) {
    const int r = ty * 4 + yy;     // d-local
    xs[r][tx] = b2f(X[(size_t)(i0 + r) * 4096 + j0 + tx]);   // xs[d][j]
  }
  __syncthreads();
  if (b < 2) {
    u16* T = b ? Vt : Gt;
#pragma unroll
    for (int yy = 0; yy < 4; ++yy) {
      const int rr = ty * 4 + yy;  // j-local
      const size_t idx = (size_t)(j0 + rr) * 1024 + i0 + tx;
      T[idx] = f2b(b2f(T[idx]) - 0.1f * xs[tx][rr]);
    }
  } else {
#pragma unroll
    for (int yy = 0; yy < 4; ++yy) {
      const int rr = ty * 4 + yy;  // j-local
      const size_t idx = (size_t)(j0 + rr) * 1024 + i0 + tx;
      const float nv = b2f(Pb[idx]) - 0.1f * xs[tx][rr];
      const u16 nb = f2b(nv);
      Pb[idx] = nb;
      ns[rr][tx] = nb;             // ns[j][d]
    }
    __syncthreads();
#pragma unroll
    for (int yy = 0; yy < 4; ++yy) {
      const int rr = ty * 4 + yy;  // d-local
      Pt[(size_t)(i0 + rr) * 4096 + j0 + tx] = ns[tx][rr];
    }
  }
}

static GA mkga(const u16* A, const u16* B, void* C, int M, int K, int lda, int ldb, int ldc,
               u16* O1 = nullptr, int ldo1 = 0, const void* E0 = nullptr, int lde0 = 0,
               const u16* E1 = nullptr, int lde1 = 0, float p0 = 0.f, float p1 = 0.f) {
  GA a{};
  a.A[0] = A; a.B[0] = B; a.C[0] = C; a.O1[0] = O1; a.E0[0] = E0; a.E1[0] = E1;
  a.lda[0] = a.lda[1] = a.lda[2] = lda;
  a.ldb[0] = a.ldb[1] = a.ldb[2] = ldb;
  a.M = M; a.K = K; a.ldc = ldc;
  a.ldo1 = ldo1; a.lde0 = lde0; a.lde1 = lde1; a.p0 = p0; a.p1 = p1;
  return a;
}

extern "C" void kernel_launch(void* const* d_in, const int* in_sizes, int n_in,
                              void* d_out, int out_size, void* d_ws, size_t ws_size,
                              hipStream_t stream) {
  (void)in_sizes; (void)n_in;
  const float* x      = (const float*)d_in[0];
  const float* qkv_w  = (const float*)d_in[1];
  const float* qkv_b  = (const float*)d_in[2];
  const float* qn_s   = (const float*)d_in[3];
  const float* qn_b   = (const float*)d_in[4];
  const float* kn_s   = (const float*)d_in[5];
  const float* kn_b   = (const float*)d_in[6];
  const float* g_gate = (const float*)d_in[7];
  const float* g_val  = (const float*)d_in[8];
  const float* g_proj = (const float*)d_in[9];
  const float* proj_w = (const float*)d_in[10];
  const float* proj_b = (const float*)d_in[11];
  float* out = (float*)d_out;

  const size_t PM = 4194304;                 // 1024*4096
  const size_t TD = (size_t)NTOKA * 1024;    // 11,534,336
  const size_t THC = (size_t)CHK * 4096;     // 5,767,168 elements

  // ---- footprint check: persistent 127,926,528 + arena 125,304,832 = 253,231,360 B ----
  const size_t NEED = 253231360 + 4096;
  if (ws_size < NEED) {
    // diagnostic: absmax will report ws_size in MiB
    diag_k<<<dim3((out_size + 255) / 256), dim3(256), 0, stream>>>(out, out_size,
                                                                   (float)(ws_size >> 20));
    return;
  }

  char* p = (char*)d_ws;
  auto carve = [&](size_t bytes) { char* r = p; p += (bytes + 255) & ~(size_t)255; return (void*)r; };

  // ---- persistent (127.9 MB) ----
  u16* Gt     = (u16*)carve(PM * 2);         // G^T  [4096,1024]
  u16* Vt     = (u16*)carve(PM * 2);         // V^T  [4096,1024]
  u16* Pt     = (u16*)carve(PM * 2);         // P^T  [1024,4096]
  u16* Pb     = (u16*)carve(PM * 2);         // P    [4096,1024]
  u16* projWt = (u16*)carve(1048576ull * 2);
  u16* qb     = (u16*)carve(TD * 2);
  u16* kb     = (u16*)carve(TD * 2);
  u16* vb     = (u16*)carve(TD * 2);
  u16* kT     = (u16*)carve(TD * 2);
  float* ssq  = (float*)carve(256);
  char* arena = p;                           // 125.3 MB phase-aliased

  // P0 staging
  u16* xb    = (u16*)arena;                                   // 23,068,672 B
  u16* qkvWt = (u16*)(arena + 23068672);                      //  6,291,456
  u16* qkvB  = (u16*)(arena + 29360128);                      // 67,534,848 (NTOK x 3072)
  // P1 backward per chunk
  u16* zzz    = (u16*)arena;                                  // 3 x 11,534,336 (zg|zv|h)
  u16* T3     = (u16*)(arena + 34603008);                     // 3 x 11,534,336
  u16* dpredb = (u16*)(arena + 69206016);                     //  2,883,584
  u16* dpredT = (u16*)(arena + 72089600);                     //  2,883,584
  float* gAll = (float*)(arena + 74973184);                   // 50,331,648 -> end 125,304,832
  // P2 Newton-Schulz (gAll dead after scale_k)
  u16* XAb  = (u16*)arena;                                    // 25,165,824
  u16* XAbT = (u16*)(arena + 25165824);
  u16* XBb  = (u16*)(arena + 50331648);
  u16* XBbT = (u16*)(arena + 75497472);
  u16* Ab   = (u16*)(arena + 100663296);                      //  6,291,456
  u16* Wb   = (u16*)(arena + 106954752);                      //  6,291,456 -> 113,246,208
  // P4 final forward per chunk
  u16* zgc = (u16*)arena;                                     // 23,068,672
  u16* hc  = (u16*)(arena + 23068672);                        // 23,068,672
  u16* oc  = (u16*)(arena + 46137344);                        //  5,767,168

  const dim3 blk(256), tb32(32, 8);
  const float inv2 = 2.0f / (10992.0f * 1024.0f);
  const float nsa = 3.4445f, nsb = -4.7750f, nsc = 2.0315f;

  // ---- setup: bf16 conversions + transposed weights ----
  cvt_k<<<dim3(43968), blk, 0, stream>>>(x, xb, NTOK * 1024);
  cvt_k<<<dim3(16384), blk, 0, stream>>>(g_proj, Pb, (int)PM);
  tr_f32b<<<dim3(96, 32), tb32, 0, stream>>>(qkv_w, qkvWt, 3072, 1024);
  tr_f32b<<<dim3(32, 32), tb32, 0, stream>>>(proj_w, projWt, 1024, 1024);
  tr_f32b<<<dim3(128, 32), tb32, 0, stream>>>(g_gate, Gt, 4096, 1024);
  tr_f32b<<<dim3(128, 32), tb32, 0, stream>>>(g_val, Vt, 4096, 1024);
  tr_f32b<<<dim3(32, 128), tb32, 0, stream>>>(g_proj, Pt, 1024, 4096);

  gemm_bt<1, 1><<<dim3(24, 88, 1), blk, 0, stream>>>(
      mkga(xb, qkvWt, qkvB, NTOK, 1024, 1024, 1024, 3072, nullptr, 0, qkv_b, 0));
  norm_qkv<<<dim3(NTOK), blk, 0, stream>>>(qkvB, qn_s, qn_b, kn_s, kn_b, qb, kb, vb);
  tr_b16<<<dim3(32, 352, 1), tb32, 0, stream>>>(kb, kT, 1024, NTOKA, NTOK, 0, 0);

  // ---- 2 TTT steps ----
  for (int step = 0; step < 2; ++step) {
    hipMemsetAsync(gAll, 0, 3 * PM * 4, stream);
    for (int c = 0; c < NCH; ++c) {
      const int c0 = c * CHK;
      const int vc = (NTOK - c0 < CHK) ? (NTOK - c0) : CHK;
      const u16* kc = kb + (size_t)c0 * 1024;
      u16 *zg = zzz, *zv = zzz + THC, *hh = zzz + 2 * THC;
      gemm_bt<0, 1><<<dim3(32, 11, 1), blk, 0, stream>>>(
          mkga(kc, Gt, zg, vc, 1024, 1024, 1024, 4096));
      gemm_bt<3, 1><<<dim3(32, 11, 1), blk, 0, stream>>>(
          mkga(kc, Vt, zv, vc, 1024, 1024, 1024, 4096, hh, 4096, zg, 4096));
      gemm_bt<2, 1><<<dim3(8, 11, 1), blk, 0, stream>>>(
          mkga(hh, Pt, dpredb, vc, 4096, 4096, 4096, 1024, nullptr, 0,
               vb + (size_t)c0 * 1024, 1024, nullptr, 0, inv2, 0.f));
      gemm_bt<5, 1><<<dim3(32, 11, 1), blk, 0, stream>>>(
          mkga(dpredb, Pb, zg, vc, 1024, 1024, 1024, 4096, zv, 4096, zg, 4096, zv, 4096));
      tr_b16<<<dim3(128, 44, 3), tb32, 0, stream>>>(zzz, T3, 4096, CHK, vc, THC, THC);
      tr_b16<<<dim3(32, 44, 1), tb32, 0, stream>>>(dpredb, dpredT, 1024, CHK, vc, 0, 0);
      {
        GA a{};
        a.A[0] = kT + c0; a.A[1] = kT + c0; a.A[2] = dpredT;
        a.lda[0] = NTOKA; a.lda[1] = NTOKA; a.lda[2] = CHK;
        a.B[0] = T3; a.B[1] = T3 + THC; a.B[2] = T3 + 2 * THC;
        a.ldb[0] = a.ldb[1] = a.ldb[2] = CHK;
        a.C[0] = gAll; a.C[1] = gAll + PM; a.C[2] = gAll + 2 * PM;
        a.M = 1024; a.K = CHK; a.ldc = 4096;
        gemm_bt<8, 0><<<dim3(32, 8, 3), blk, 0, stream>>>(a);
      }
    }
    // X0 = g/||g||_F (bf16)
    hipMemsetAsync(ssq, 0, 16, stream);
    sumsq_k<<<dim3(512, 3), blk, 0, stream>>>(gAll, ssq);
    scale_k<<<dim3(2048, 3), blk, 0, stream>>>(gAll, ssq, XAb);
    tr_b16<<<dim3(128, 32, 3), tb32, 0, stream>>>(XAb, XAbT, 4096, 1024, 1024, PM, PM);

    // Newton-Schulz x5, batched z=3, bf16
    u16* Xi_b = XAb; u16* Xi_bT = XAbT;
    u16* Xo_b = XBb; u16* Xo_bT = XBbT;
    for (int it = 0; it < 5; ++it) {
      {  // Ab = X@X^T (symmetric, bf16)
        GA a{};
        for (int b = 0; b < 3; ++b) {
          a.A[b] = Xi_b + (size_t)b * PM; a.B[b] = Xi_b + (size_t)b * PM;
          a.C[b] = Ab + (size_t)b * 1048576;
          a.lda[b] = 4096; a.ldb[b] = 4096;
        }
        a.M = 1024; a.K = 4096; a.ldc = 1024;
        gemm_bt<0, 1><<<dim3(8, 8, 3), blk, 0, stream>>>(a);
      }
      {  // W = nsb*A + nsc*A@A
        GA a{};
        for (int b = 0; b < 3; ++b) {
          a.A[b] = Ab + (size_t)b * 1048576; a.B[b] = Ab + (size_t)b * 1048576;
          a.C[b] = Wb + (size_t)b * 1048576; a.E0[b] = Ab + (size_t)b * 1048576;
          a.lda[b] = 1024; a.ldb[b] = 1024;
        }
        a.M = 1024; a.K = 1024; a.ldc = 1024; a.lde0 = 1024; a.p0 = nsb; a.p1 = nsc;
        gemm_bt<7, 1><<<dim3(8, 8, 3), blk, 0, stream>>>(a);
      }
      {  // Xn = nsa*X + W@X
        GA a{};
        for (int b = 0; b < 3; ++b) {
          a.A[b] = Wb + (size_t)b * 1048576; a.B[b] = Xi_bT + (size_t)b * PM;
          a.C[b] = Xo_b + (size_t)b * PM; a.E0[b] = Xi_b + (size_t)b * PM;
          a.lda[b] = 1024; a.ldb[b] = 1024;
        }
        a.M = 1024; a.K = 1024; a.ldc = 4096; a.lde0 = 4096; a.p0 = nsa; a.p1 = 1.f;
        gemm_bt<7, 1><<<dim3(32, 8, 3), blk, 0, stream>>>(a);
      }
      tr_b16<<<dim3(128, 32, 3), tb32, 0, stream>>>(Xo_b, Xo_bT, 4096, 1024, 1024, PM, PM);
      u16* tb = Xi_b; Xi_b = Xo_b; Xo_b = tb;
      u16* tt = Xi_bT; Xi_bT = Xo_bT; Xo_bT = tt;
    }
    muon_apply<<<dim3(128, 32, 3), tb32, 0, stream>>>(Xi_b, Gt, Vt, Pt, Pb);
  }

  // ---- final forward with q, chunked ----
  for (int c = 0; c < NCH2; ++c) {
    const int c0 = c * CHK2;
    const int vc = (NTOK - c0 < CHK2) ? (NTOK - c0) : CHK2;
    const u16* qc = qb + (size_t)c0 * 1024;
    gemm_bt<0, 1><<<dim3(32, 22, 1), blk, 0, stream>>>(
        mkga(qc, Gt, zgc, vc, 1024, 1024, 1024, 4096));
    gemm_bt<4, 1><<<dim3(32, 22, 1), blk, 0, stream>>>(
        mkga(qc, Vt, hc, vc, 1024, 1024, 1024, 4096, nullptr, 0, zgc, 4096));
    gemm_bt<0, 1><<<dim3(8, 22, 1), blk, 0, stream>>>(
        mkga(hc, Pt, oc, vc, 4096, 4096, 4096, 1024));
    gemm_bt<1, 0><<<dim3(8, 22, 1), blk, 0, stream>>>(
        mkga(oc, projWt, out + (size_t)c0 * 1024, vc, 1024, 1024, 1024, 1024,
             nullptr, 0, proj_b, 0));
  }
}

// Round 4
// 6729.906 us; speedup vs baseline: 1.0784x; 1.0784x over previous
//
#include <hip/hip_runtime.h>
#include <stdint.h>

#define NTOK 10992      // B*SN
#define NTOKA 11264     // padded token dim (8*1408)
#define CHK 1408        // backward token chunk (11*128)
#define NCH 8
#define FCHK 5632       // final-forward chunk
#define PMi 4194304

typedef unsigned short u16;
typedef __attribute__((ext_vector_type(8))) __bf16 b8;
typedef __attribute__((ext_vector_type(4))) float f32x4;

__device__ __forceinline__ u16 f2b(float f) {
  union { float f; uint32_t u; } v; v.f = f;
  return (u16)((v.u + 0x7fffu + ((v.u >> 16) & 1u)) >> 16);   // RNE
}
__device__ __forceinline__ float b2f(u16 b) {
  union { uint32_t u; float f; } v; v.u = ((uint32_t)b) << 16; return v.f;
}
__device__ __forceinline__ uint2 pk4(u16 a, u16 b, u16 c, u16 d) {
  uint2 r; r.x = (uint32_t)a | ((uint32_t)b << 16); r.y = (uint32_t)c | ((uint32_t)d << 16);
  return r;
}
__device__ __forceinline__ void gload16(const u16* g, u16* l) {
  __builtin_amdgcn_global_load_lds((const __attribute__((address_space(1))) void*)(const void*)g,
                                   (__attribute__((address_space(3))) void*)(void*)l, 16, 0, 0);
}

struct GA {
  const u16* A[3]; const u16* B[3];
  void* C[3]; u16* O1[3]; u16* OT[3];
  const void* E0[3]; const u16* E1[3];
  int lda[3], ldb[3];
  int M, N, K, ldc, ldo1, ldt, lde0, lde1;
  float p0, p1;
};

// ---------------- 128x128 tile GEMM: C[m,n] = sum_k A[m,k]*B[n,k] ----------------
// EPI: 0 Cb=acc | 1 Cb=acc+E0f[n] | 3 Cb=acc(zv), h=swish(E0b)*acc -> O1 + OT(T-pack)
//      4 Cb=swish(E0b)*acc (in-place ok) | 5 dzg->C(T-pack), dzv->O1(T-pack)
//      6 Cf=acc+E0f[n] | 8 atomicAdd(Cf, acc) | 9 Cb=p0*E0b+acc, + OT(T-pack)
template <int EPI, int SPLIT>
__global__ __launch_bounds__(256, 2) void gemm_bt(GA g) {
  __shared__ u16 As[128 * 32];
  __shared__ u16 Bs[128 * 32];
  int bz = blockIdx.z, koff = 0, klen = g.K;
  if constexpr (SPLIT) { koff = (bz & 1) * (g.K >> 1); bz >>= 1; klen = g.K >> 1; }
  const u16* __restrict__ A = g.A[bz] + koff;
  const u16* __restrict__ B = g.B[bz] + koff;
  const int lda = g.lda[bz], ldb = g.ldb[bz];
  const int m0 = blockIdx.y * 128, n0 = blockIdx.x * 128;
  const int tid = threadIdx.x, w = tid >> 6, lane = tid & 63;
  const int wr = (w >> 1) * 64, wc = (w & 1) * 64;
  const int ln = lane & 15, lq = lane >> 4;

  f32x4 acc[4][4];
#pragma unroll
  for (int i = 0; i < 4; ++i)
#pragma unroll
    for (int j = 0; j < 4; ++j)
#pragma unroll
      for (int r = 0; r < 4; ++r) acc[i][j][r] = 0.f;

  const u16* Ag = A + (size_t)(m0 + 32 * w + (lane >> 2)) * lda + (lane & 3) * 8;
  const u16* Bg = B + (size_t)(n0 + 32 * w + (lane >> 2)) * ldb + (lane & 3) * 8;
  u16* AsW = &As[w * 1024];
  u16* BsW = &Bs[w * 1024];
  const int nkt = klen >> 5;

  for (int kt = 0; kt < nkt; ++kt) {
    __syncthreads();
    gload16(Ag, AsW);
    gload16(Ag + (size_t)16 * lda, AsW + 512);
    gload16(Bg, BsW);
    gload16(Bg + (size_t)16 * ldb, BsW + 512);
    Ag += 32; Bg += 32;
    __syncthreads();
    b8 af[4], bfr[4];
#pragma unroll
    for (int i = 0; i < 4; ++i) af[i] = *(const b8*)&As[(wr + i * 16 + ln) * 32 + lq * 8];
#pragma unroll
    for (int j = 0; j < 4; ++j) bfr[j] = *(const b8*)&Bs[(wc + j * 16 + ln) * 32 + lq * 8];
#pragma unroll
    for (int i = 0; i < 4; ++i)
#pragma unroll
      for (int j = 0; j < 4; ++j)
        acc[i][j] = __builtin_amdgcn_mfma_f32_16x16x32_bf16(af[i], bfr[j], acc[i][j], 0, 0, 0);
  }

  float* Cf = (float*)g.C[bz];
  u16* Cb = (u16*)g.C[bz];
  u16* O1 = g.O1[bz];
  u16* OT = g.OT[bz];
  const float* E0f = (const float*)g.E0[bz];
  const u16* E0b = (const u16*)g.E0[bz];
  const u16* E1b = g.E1[bz];

#pragma unroll
  for (int i = 0; i < 4; ++i) {
    const int mb = m0 + wr + i * 16 + lq * 4;
    if (mb >= g.M) continue;
#pragma unroll
    for (int j = 0; j < 4; ++j) {
      const int n = n0 + wc + j * 16 + ln;
      if (n >= g.N) continue;
      float vv[4];
#pragma unroll
      for (int r = 0; r < 4; ++r) vv[r] = acc[i][j][r];
      if constexpr (EPI == 0) {
#pragma unroll
        for (int r = 0; r < 4; ++r) Cb[(size_t)(mb + r) * g.ldc + n] = f2b(vv[r]);
      } else if constexpr (EPI == 1) {
        const float bias = E0f[n];
#pragma unroll
        for (int r = 0; r < 4; ++r) Cb[(size_t)(mb + r) * g.ldc + n] = f2b(vv[r] + bias);
      } else if constexpr (EPI == 3) {
        u16 oq[4];
#pragma unroll
        for (int r = 0; r < 4; ++r) {
          const int m = mb + r;
          Cb[(size_t)m * g.ldc + n] = f2b(vv[r]);
          const float zg = b2f(E0b[(size_t)m * g.lde0 + n]);
          const float s = 1.f / (1.f + __expf(-zg));
          const u16 ub = f2b(zg * s * vv[r]);
          O1[(size_t)m * g.ldo1 + n] = ub;
          oq[r] = ub;
        }
        *(uint2*)&OT[(size_t)n * g.ldt + mb] = pk4(oq[0], oq[1], oq[2], oq[3]);
      } else if constexpr (EPI == 4) {
#pragma unroll
        for (int r = 0; r < 4; ++r) {
          const int m = mb + r;
          const float zg = b2f(E0b[(size_t)m * g.lde0 + n]);
          const float s = 1.f / (1.f + __expf(-zg));
          Cb[(size_t)m * g.ldc + n] = f2b(zg * s * vv[r]);
        }
      } else if constexpr (EPI == 5) {
        u16 cq[4], oq[4];
#pragma unroll
        for (int r = 0; r < 4; ++r) {
          const int m = mb + r;
          const float zg = b2f(E0b[(size_t)m * g.lde0 + n]);
          const float zv = b2f(E1b[(size_t)m * g.lde1 + n]);
          const float s = 1.f / (1.f + __expf(-zg));
          cq[r] = f2b(vv[r] * zv * s * (1.f + zg * (1.f - s)));
          oq[r] = f2b(vv[r] * zg * s);
        }
        *(uint2*)&Cb[(size_t)n * g.ldt + mb] = pk4(cq[0], cq[1], cq[2], cq[3]);
        *(uint2*)&O1[(size_t)n * g.ldt + mb] = pk4(oq[0], oq[1], oq[2], oq[3]);
      } else if constexpr (EPI == 6) {
        const float bias = E0f[n];
#pragma unroll
        for (int r = 0; r < 4; ++r) Cf[(size_t)(mb + r) * g.ldc + n] = vv[r] + bias;
      } else if constexpr (EPI == 8) {
#pragma unroll
        for (int r = 0; r < 4; ++r) atomicAdd(&Cf[(size_t)(mb + r) * g.ldc + n], vv[r]);
      } else if constexpr (EPI == 9) {
        u16 cq[4];
#pragma unroll
        for (int r = 0; r < 4; ++r) {
          const int m = mb + r;
          const u16 ub = f2b(g.p0 * b2f(E0b[(size_t)m * g.lde0 + n]) + vv[r]);
          Cb[(size_t)m * g.ldc + n] = ub;
          cq[r] = ub;
        }
        *(uint2*)&OT[(size_t)n * g.ldt + mb] = pk4(cq[0], cq[1], cq[2], cq[3]);
      }
    }
  }
}

// ---------------- 64x64 tile GEMM (for small-N shapes) ----------------
// EPI: 0 Cb=acc | 2 v=(acc-E0b)*p0 -> Cb + OT(T-pack) | 6 Cf=acc+E0f[n] | 7 Cb=p0*E0b+p1*acc
template <int EPI>
__global__ __launch_bounds__(256, 2) void gemm64(GA g) {
  __shared__ u16 As[64 * 32];
  __shared__ u16 Bs[64 * 32];
  const int bz = blockIdx.z;
  const u16* __restrict__ A = g.A[bz];
  const u16* __restrict__ B = g.B[bz];
  const int lda = g.lda[bz], ldb = g.ldb[bz];
  const int m0 = blockIdx.y * 64, n0 = blockIdx.x * 64;
  const int tid = threadIdx.x, w = tid >> 6, lane = tid & 63;
  const int wr = (w >> 1) * 32, wc = (w & 1) * 32;
  const int ln = lane & 15, lq = lane >> 4;

  f32x4 acc[2][2];
#pragma unroll
  for (int i = 0; i < 2; ++i)
#pragma unroll
    for (int j = 0; j < 2; ++j)
#pragma unroll
      for (int r = 0; r < 4; ++r) acc[i][j][r] = 0.f;

  const u16* Ag = A + (size_t)(m0 + 16 * w + (lane >> 2)) * lda + (lane & 3) * 8;
  const u16* Bg = B + (size_t)(n0 + 16 * w + (lane >> 2)) * ldb + (lane & 3) * 8;
  u16* AsW = &As[w * 512];
  u16* BsW = &Bs[w * 512];
  const int nkt = g.K >> 5;

  for (int kt = 0; kt < nkt; ++kt) {
    __syncthreads();
    gload16(Ag, AsW);
    gload16(Bg, BsW);
    Ag += 32; Bg += 32;
    __syncthreads();
    b8 af[2], bfr[2];
#pragma unroll
    for (int i = 0; i < 2; ++i) af[i] = *(const b8*)&As[(wr + i * 16 + ln) * 32 + lq * 8];
#pragma unroll
    for (int j = 0; j < 2; ++j) bfr[j] = *(const b8*)&Bs[(wc + j * 16 + ln) * 32 + lq * 8];
#pragma unroll
    for (int i = 0; i < 2; ++i)
#pragma unroll
      for (int j = 0; j < 2; ++j)
        acc[i][j] = __builtin_amdgcn_mfma_f32_16x16x32_bf16(af[i], bfr[j], acc[i][j], 0, 0, 0);
  }

  float* Cf = (float*)g.C[bz];
  u16* Cb = (u16*)g.C[bz];
  u16* OT = g.OT[bz];
  const float* E0f = (const float*)g.E0[bz];
  const u16* E0b = (const u16*)g.E0[bz];

#pragma unroll
  for (int i = 0; i < 2; ++i) {
    const int mb = m0 + wr + i * 16 + lq * 4;
    if (mb >= g.M) continue;
#pragma unroll
    for (int j = 0; j < 2; ++j) {
      const int n = n0 + wc + j * 16 + ln;
      if (n >= g.N) continue;
      float vv[4];
#pragma unroll
      for (int r = 0; r < 4; ++r) vv[r] = acc[i][j][r];
      if constexpr (EPI == 0) {
#pragma unroll
        for (int r = 0; r < 4; ++r) Cb[(size_t)(mb + r) * g.ldc + n] = f2b(vv[r]);
      } else if constexpr (EPI == 2) {
        u16 cq[4];
#pragma unroll
        for (int r = 0; r < 4; ++r) {
          const int m = mb + r;
          const u16 ub = f2b((vv[r] - b2f(E0b[(size_t)m * g.lde0 + n])) * g.p0);
          Cb[(size_t)m * g.ldc + n] = ub;
          cq[r] = ub;
        }
        *(uint2*)&OT[(size_t)n * g.ldt + mb] = pk4(cq[0], cq[1], cq[2], cq[3]);
      } else if constexpr (EPI == 6) {
        const float bias = E0f[n];
#pragma unroll
        for (int r = 0; r < 4; ++r) Cf[(size_t)(mb + r) * g.ldc + n] = vv[r] + bias;
      } else if constexpr (EPI == 7) {
#pragma unroll
        for (int r = 0; r < 4; ++r) {
          const int m = mb + r;
          Cb[(size_t)m * g.ldc + n] =
              f2b(g.p0 * b2f(E0b[(size_t)m * g.lde0 + n]) + g.p1 * vv[r]);
        }
      }
    }
  }
}

__global__ __launch_bounds__(256) void norm_qkv(const u16* __restrict__ qkvB,
    const float* __restrict__ qs, const float* __restrict__ qbi,
    const float* __restrict__ ks, const float* __restrict__ kbi,
    u16* __restrict__ qb, u16* __restrict__ kb, u16* __restrict__ vb) {
  const int tok = blockIdx.x;
  const int t = threadIdx.x;
  const int d = t * 4;
  const u16* row = qkvB + (size_t)tok * 3072;
  const uint2 qu = *(const uint2*)(row + d);
  const uint2 ku = *(const uint2*)(row + 1024 + d);
  *(uint2*)(vb + (size_t)tok * 1024 + d) = *(const uint2*)(row + 2048 + d);
  float q0 = b2f(qu.x & 0xffff), q1 = b2f(qu.x >> 16), q2 = b2f(qu.y & 0xffff), q3 = b2f(qu.y >> 16);
  float k0 = b2f(ku.x & 0xffff), k1 = b2f(ku.x >> 16), k2 = b2f(ku.y & 0xffff), k3 = b2f(ku.y >> 16);
  float sq = q0 * q0 + q1 * q1 + q2 * q2 + q3 * q3;
  float sk = k0 * k0 + k1 * k1 + k2 * k2 + k3 * k3;
  for (int off = 1; off < 16; off <<= 1) { sq += __shfl_xor(sq, off); sk += __shfl_xor(sk, off); }
  const float rq = 1.f / (sqrtf(sq) + 1e-6f);
  const float rk = 1.f / (sqrtf(sk) + 1e-6f);
  const int hd = d & 63;
  const float4 qsv = *(const float4*)(qs + hd);
  const float4 qbv = *(const float4*)(qbi + hd);
  const float4 ksv = *(const float4*)(ks + hd);
  const float4 kbv = *(const float4*)(kbi + hd);
  uint64_t pq = (uint64_t)f2b(q0 * rq * qsv.x + qbv.x)
              | ((uint64_t)f2b(q1 * rq * qsv.y + qbv.y) << 16)
              | ((uint64_t)f2b(q2 * rq * qsv.z + qbv.z) << 32)
              | ((uint64_t)f2b(q3 * rq * qsv.w + qbv.w) << 48);
  uint64_t pk = (uint64_t)f2b(k0 * rk * ksv.x + kbv.x)
              | ((uint64_t)f2b(k1 * rk * ksv.y + kbv.y) << 16)
              | ((uint64_t)f2b(k2 * rk * ksv.z + kbv.z) << 32)
              | ((uint64_t)f2b(k3 * rk * ksv.w + kbv.w) << 48);
  *(uint64_t*)(qb + (size_t)tok * 1024 + d) = pq;
  *(uint64_t*)(kb + (size_t)tok * 1024 + d) = pk;
}

__global__ __launch_bounds__(256) void tr_b16(const u16* __restrict__ in, u16* __restrict__ out,
                                              int Cin, int Rtot, int Rval,
                                              size_t inStr, size_t outStr) {
  const int b = blockIdx.z;
  in += (size_t)b * inStr; out += (size_t)b * outStr;
  __shared__ u16 t[32][33];
  const int c0 = blockIdx.x * 32, r0 = blockIdx.y * 32;
  const int tx = threadIdx.x, ty = threadIdx.y;
#pragma unroll
  for (int yy = 0; yy < 4; ++yy) {
    const int rr = ty * 4 + yy;
    const int r = r0 + rr;
    t[rr][tx] = (r < Rval) ? in[(size_t)r * Cin + c0 + tx] : (u16)0;
  }
  __syncthreads();
#pragma unroll
  for (int yy = 0; yy < 4; ++yy) {
    const int cc = ty * 4 + yy;
    out[(size_t)(c0 + cc) * Rtot + r0 + tx] = t[tx][cc];
  }
}

__global__ __launch_bounds__(256) void tr_f32b(const float* __restrict__ in, u16* __restrict__ out,
                                               int Cin, int Rtot) {
  __shared__ u16 t[32][33];
  const int c0 = blockIdx.x * 32, r0 = blockIdx.y * 32;
  const int tx = threadIdx.x, ty = threadIdx.y;
#pragma unroll
  for (int yy = 0; yy < 4; ++yy) {
    const int rr = ty * 4 + yy;
    t[rr][tx] = f2b(in[(size_t)(r0 + rr) * Cin + c0 + tx]);
  }
  __syncthreads();
#pragma unroll
  for (int yy = 0; yy < 4; ++yy) {
    const int cc = ty * 4 + yy;
    out[(size_t)(c0 + cc) * Rtot + r0 + tx] = t[tx][cc];
  }
}

__global__ void cvt_k(const float* __restrict__ in, u16* __restrict__ out, int n) {
  const int i = blockIdx.x * 256 + threadIdx.x;
  if (i < n) out[i] = f2b(in[i]);
}

__global__ void diag_k(float* __restrict__ out, int n, float val) {
  const int i = blockIdx.x * 256 + threadIdx.x;
  if (i < n) out[i] = val;
}

__global__ __launch_bounds__(256) void sumsq_k(const float* __restrict__ g, float* __restrict__ out) {
  const int b = blockIdx.y;
  const float* p = g + (size_t)b * PMi;
  float s = 0.f;
  for (int i = blockIdx.x * 256 + threadIdx.x; i < PMi; i += gridDim.x * 256) {
    float v = p[i]; s += v * v;
  }
  for (int off = 32; off > 0; off >>= 1) s += __shfl_xor(s, off);
  __shared__ float red[4];
  if ((threadIdx.x & 63) == 0) red[threadIdx.x >> 6] = s;
  __syncthreads();
  if (threadIdx.x == 0) atomicAdd(out + b, red[0] + red[1] + red[2] + red[3]);
}

__global__ __launch_bounds__(256) void scale_k(const float* __restrict__ g, const float* __restrict__ ss,
                                               u16* __restrict__ Xb) {
  const int b = blockIdx.y;
  const float r = 1.f / (sqrtf(ss[b]) + 1e-7f);
  const size_t o = (size_t)b * PMi;
  for (int i = blockIdx.x * 256 + threadIdx.x; i < PMi; i += gridDim.x * 256)
    Xb[o + i] = f2b(g[o + i] * r);
}

__global__ __launch_bounds__(256) void muon_apply(const u16* __restrict__ Xb_,
    u16* __restrict__ Gt, u16* __restrict__ Vt, u16* __restrict__ Pt, u16* __restrict__ Pb) {
  const int b = blockIdx.z;
  __shared__ float xs[32][33];
  __shared__ u16 ns[32][33];
  const int j0 = blockIdx.x * 32;
  const int i0 = blockIdx.y * 32;
  const u16* X = Xb_ + (size_t)b * PMi;
  const int tx = threadIdx.x, ty = threadIdx.y;
#pragma unroll
  for (int yy = 0; yy < 4; ++yy) {
    const int r = ty * 4 + yy;
    xs[r][tx] = b2f(X[(size_t)(i0 + r) * 4096 + j0 + tx]);
  }
  __syncthreads();
  if (b < 2) {
    u16* T = b ? Vt : Gt;
#pragma unroll
    for (int yy = 0; yy < 4; ++yy) {
      const int rr = ty * 4 + yy;
      const size_t idx = (size_t)(j0 + rr) * 1024 + i0 + tx;
      T[idx] = f2b(b2f(T[idx]) - 0.1f * xs[tx][rr]);
    }
  } else {
#pragma unroll
    for (int yy = 0; yy < 4; ++yy) {
      const int rr = ty * 4 + yy;
      const size_t idx = (size_t)(j0 + rr) * 1024 + i0 + tx;
      const float nv = b2f(Pb[idx]) - 0.1f * xs[tx][rr];
      const u16 nb = f2b(nv);
      Pb[idx] = nb;
      ns[rr][tx] = nb;
    }
    __syncthreads();
#pragma unroll
    for (int yy = 0; yy < 4; ++yy) {
      const int rr = ty * 4 + yy;
      Pt[(size_t)(i0 + rr) * 4096 + j0 + tx] = ns[tx][rr];
    }
  }
}

static GA mk(const u16* A, const u16* B, void* C, int M, int N, int K,
             int lda, int ldb, int ldc) {
  GA a{};
  a.A[0] = a.A[1] = a.A[2] = A;
  a.B[0] = a.B[1] = a.B[2] = B;
  a.C[0] = a.C[1] = a.C[2] = C;
  a.lda[0] = a.lda[1] = a.lda[2] = lda;
  a.ldb[0] = a.ldb[1] = a.ldb[2] = ldb;
  a.M = M; a.N = N; a.K = K; a.ldc = ldc;
  return a;
}

extern "C" void kernel_launch(void* const* d_in, const int* in_sizes, int n_in,
                              void* d_out, int out_size, void* d_ws, size_t ws_size,
                              hipStream_t stream) {
  (void)in_sizes; (void)n_in;
  const float* x      = (const float*)d_in[0];
  const float* qkv_w  = (const float*)d_in[1];
  const float* qkv_b  = (const float*)d_in[2];
  const float* qn_s   = (const float*)d_in[3];
  const float* qn_b   = (const float*)d_in[4];
  const float* kn_s   = (const float*)d_in[5];
  const float* kn_b   = (const float*)d_in[6];
  const float* g_gate = (const float*)d_in[7];
  const float* g_val  = (const float*)d_in[8];
  const float* g_proj = (const float*)d_in[9];
  const float* proj_w = (const float*)d_in[10];
  const float* proj_b = (const float*)d_in[11];
  float* out = (float*)d_out;

  const size_t PM = PMi;
  const size_t TD = (size_t)NTOKA * 1024;

  const size_t NEED = 253231360 + 4096;
  if (ws_size < NEED) {
    diag_k<<<dim3((out_size + 255) / 256), dim3(256), 0, stream>>>(out, out_size,
                                                                   (float)(ws_size >> 20));
    return;
  }

  char* p = (char*)d_ws;
  auto carve = [&](size_t bytes) { char* r = p; p += (bytes + 255) & ~(size_t)255; return (void*)r; };
  auto cdiv = [](int a, int b) { return (a + b - 1) / b; };

  // ---- persistent (127.93 MB) ----
  u16* Gt     = (u16*)carve(PM * 2);         // G^T [4096,1024]
  u16* Vt     = (u16*)carve(PM * 2);         // V^T [4096,1024]
  u16* Pt     = (u16*)carve(PM * 2);         // P^T [1024,4096]
  u16* Pb     = (u16*)carve(PM * 2);         // P   [4096,1024]
  u16* projWt = (u16*)carve(1048576ull * 2);
  u16* qb     = (u16*)carve(TD * 2);
  u16* kb     = (u16*)carve(TD * 2);
  u16* vT     = (u16*)carve(TD * 2);         // v^T [1024, NTOKA]
  u16* kT     = (u16*)carve(TD * 2);
  float* ssq  = (float*)carve(256);
  char* arena = p;                           // 125,304,832 B phase-aliased

  // P0 staging
  u16* xb     = (u16*)arena;
  u16* qkvWt  = (u16*)(arena + 23068672);
  u16* qkvB   = (u16*)(arena + 29360128);                     // NTOK x 3072
  u16* vb_tmp = (u16*)(arena + 96894976);                     // NTOK x 1024 -> 119,963,648
  // P1 backward per chunk (CHK=1408)
  u16* zg     = (u16*)arena;                                  // 11,534,336 each
  u16* zv     = (u16*)(arena + 11534336);
  u16* hh     = (u16*)(arena + 23068672);
  u16* hT     = (u16*)(arena + 34603008);                     // TBLK start
  u16* dzgT   = (u16*)(arena + 46137344);
  u16* dzvT   = (u16*)(arena + 57671680);
  u16* dpredT = (u16*)(arena + 69206016);                     // 2,883,584; TBLK end 72,089,600
  u16* dpredb = (u16*)(arena + 72089600);                     // 2,883,584
  float* gAll = (float*)(arena + 74973184);                   // 50,331,648 -> 125,304,832
  // P2 Newton-Schulz (gAll dead after scale_k)
  u16* XAb  = (u16*)arena;
  u16* XAbT = (u16*)(arena + 25165824);
  u16* XBb  = (u16*)(arena + 50331648);
  u16* XBbT = (u16*)(arena + 75497472);
  u16* Ab   = (u16*)(arena + 100663296);
  u16* Wb   = (u16*)(arena + 106954752);
  // P4 final forward per chunk (FCHK=5632)
  u16* zgc = (u16*)arena;                                     // 46,137,344 (h in-place)
  u16* oc  = (u16*)(arena + 46137344);                        // 11,534,336

  const dim3 blk(256), tb32(32, 8);
  const float inv2 = 2.0f / (10992.0f * 1024.0f);
  const float nsa = 3.4445f, nsb = -4.7750f, nsc = 2.0315f;

  // ---- setup ----
  cvt_k<<<dim3(43968), blk, 0, stream>>>(x, xb, NTOK * 1024);
  cvt_k<<<dim3(16384), blk, 0, stream>>>(g_proj, Pb, (int)PM);
  tr_f32b<<<dim3(96, 32), tb32, 0, stream>>>(qkv_w, qkvWt, 3072, 1024);
  tr_f32b<<<dim3(32, 32), tb32, 0, stream>>>(proj_w, projWt, 1024, 1024);
  tr_f32b<<<dim3(128, 32), tb32, 0, stream>>>(g_gate, Gt, 4096, 1024);
  tr_f32b<<<dim3(128, 32), tb32, 0, stream>>>(g_val, Vt, 4096, 1024);
  tr_f32b<<<dim3(32, 128), tb32, 0, stream>>>(g_proj, Pt, 1024, 4096);

  {
    GA a = mk(xb, qkvWt, qkvB, NTOK, 3072, 1024, 1024, 1024, 3072);
    a.E0[0] = a.E0[1] = a.E0[2] = qkv_b;
    gemm_bt<1, 0><<<dim3(24, 86, 1), blk, 0, stream>>>(a);
  }
  norm_qkv<<<dim3(NTOK), blk, 0, stream>>>(qkvB, qn_s, qn_b, kn_s, kn_b, qb, kb, vb_tmp);
  tr_b16<<<dim3(32, 352, 1), tb32, 0, stream>>>(kb, kT, 1024, NTOKA, NTOK, 0, 0);
  tr_b16<<<dim3(32, 352, 1), tb32, 0, stream>>>(vb_tmp, vT, 1024, NTOKA, NTOK, 0, 0);

  // ---- 2 TTT steps ----
  for (int step = 0; step < 2; ++step) {
    hipMemsetAsync(gAll, 0, 3 * PM * 4, stream);
    for (int c = 0; c < NCH; ++c) {
      const int c0 = c * CHK;
      const int vc = (NTOK - c0 < CHK) ? (NTOK - c0) : CHK;
      const int mt = cdiv(vc, 128);
      const u16* kc = kb + (size_t)c0 * 1024;
      if (vc < CHK)  // zero T-buffer tails once (last chunk): hT|dzgT|dzvT|dpredT
        hipMemsetAsync(hT, 0, 37486592, stream);
      // zg = k@G
      gemm_bt<0, 0><<<dim3(32, mt, 1), blk, 0, stream>>>(
          mk(kc, Gt, zg, vc, 4096, 1024, 1024, 1024, 4096));
      // zv = k@V ; h = swish(zg)*zv -> hh + hT
      {
        GA a = mk(kc, Vt, zv, vc, 4096, 1024, 1024, 1024, 4096);
        a.O1[0] = hh; a.ldo1 = 4096; a.OT[0] = hT; a.ldt = CHK;
        a.E0[0] = zg; a.lde0 = 4096;
        gemm_bt<3, 0><<<dim3(32, mt, 1), blk, 0, stream>>>(a);
      }
      // dpredT[d,t] = (Pt@h^T - vT)*inv2 -> dpredT + dpredb(T-pack)
      {
        GA a = mk(Pt, hh, dpredT, 1024, vc, 4096, 4096, 4096, CHK);
        a.OT[0] = dpredb; a.ldt = 1024;
        a.E0[0] = vT + c0; a.lde0 = NTOKA; a.p0 = inv2;
        gemm64<2><<<dim3(cdiv(vc, 64), 16, 1), blk, 0, stream>>>(a);
      }
      // dh = dpred@P^T -> dzgT, dzvT (T-packed)
      {
        GA a = mk(dpredb, Pb, dzgT, vc, 4096, 1024, 1024, 1024, 0);
        a.O1[0] = dzvT; a.ldt = CHK;
        a.E0[0] = zg; a.lde0 = 4096; a.E1[0] = zv; a.lde1 = 4096;
        gemm_bt<5, 0><<<dim3(32, mt, 1), blk, 0, stream>>>(a);
      }
      // grads (split-K=2, atomic): gG=kT@dzgT, gV=kT@dzvT, gP^T=dpredT@hT
      {
        GA a{};
        a.A[0] = kT + c0; a.A[1] = kT + c0; a.A[2] = dpredT;
        a.lda[0] = NTOKA; a.lda[1] = NTOKA; a.lda[2] = CHK;
        a.B[0] = dzgT; a.B[1] = dzvT; a.B[2] = hT;
        a.ldb[0] = a.ldb[1] = a.ldb[2] = CHK;
        a.C[0] = gAll; a.C[1] = gAll + PM; a.C[2] = gAll + 2 * PM;
        a.M = 1024; a.N = 4096; a.K = CHK; a.ldc = 4096;
        gemm_bt<8, 1><<<dim3(32, 8, 6), blk, 0, stream>>>(a);
      }
    }
    // X0 = g/||g||_F
    hipMemsetAsync(ssq, 0, 16, stream);
    sumsq_k<<<dim3(512, 3), blk, 0, stream>>>(gAll, ssq);
    scale_k<<<dim3(2048, 3), blk, 0, stream>>>(gAll, ssq, XAb);
    tr_b16<<<dim3(128, 32, 3), tb32, 0, stream>>>(XAb, XAbT, 4096, 1024, 1024, PM, PM);

    // Newton-Schulz x5, batched z=3
    u16* Xi_b = XAb; u16* Xi_bT = XAbT;
    u16* Xo_b = XBb; u16* Xo_bT = XBbT;
    for (int it = 0; it < 5; ++it) {
      {  // Ab = X@X^T (64-tile, grid 768)
        GA a{};
        for (int b = 0; b < 3; ++b) {
          a.A[b] = Xi_b + (size_t)b * PM; a.B[b] = Xi_b + (size_t)b * PM;
          a.C[b] = Ab + (size_t)b * 1048576;
          a.lda[b] = 4096; a.ldb[b] = 4096;
        }
        a.M = 1024; a.N = 1024; a.K = 4096; a.ldc = 1024;
        gemm64<0><<<dim3(16, 16, 3), blk, 0, stream>>>(a);
      }
      {  // W = nsb*A + nsc*A@A (64-tile)
        GA a{};
        for (int b = 0; b < 3; ++b) {
          a.A[b] = Ab + (size_t)b * 1048576; a.B[b] = Ab + (size_t)b * 1048576;
          a.C[b] = Wb + (size_t)b * 1048576; a.E0[b] = Ab + (size_t)b * 1048576;
          a.lda[b] = 1024; a.ldb[b] = 1024;
        }
        a.M = 1024; a.N = 1024; a.K = 1024; a.ldc = 1024; a.lde0 = 1024;
        a.p0 = nsb; a.p1 = nsc;
        gemm64<7><<<dim3(16, 16, 3), blk, 0, stream>>>(a);
      }
      {  // Xn = nsa*X + W@X -> Xo_b + Xo_bT (dual store)
        GA a{};
        for (int b = 0; b < 3; ++b) {
          a.A[b] = Wb + (size_t)b * 1048576; a.B[b] = Xi_bT + (size_t)b * PM;
          a.C[b] = Xo_b + (size_t)b * PM; a.OT[b] = Xo_bT + (size_t)b * PM;
          a.E0[b] = Xi_b + (size_t)b * PM;
          a.lda[b] = 1024; a.ldb[b] = 1024;
        }
        a.M = 1024; a.N = 4096; a.K = 1024; a.ldc = 4096; a.ldt = 1024;
        a.lde0 = 4096; a.p0 = nsa;
        gemm_bt<9, 0><<<dim3(32, 8, 3), blk, 0, stream>>>(a);
      }
      u16* tb = Xi_b; Xi_b = Xo_b; Xo_b = tb;
      u16* tt = Xi_bT; Xi_bT = Xo_bT; Xo_bT = tt;
    }
    muon_apply<<<dim3(128, 32, 3), tb32, 0, stream>>>(Xi_b, Gt, Vt, Pt, Pb);
  }

  // ---- final forward with q (2 chunks, h in-place over zg) ----
  for (int fc = 0; fc < 2; ++fc) {
    const int c0 = fc * FCHK;
    const int vc = (NTOK - c0 < FCHK) ? (NTOK - c0) : FCHK;
    const int mt = cdiv(vc, 128), mt64 = cdiv(vc, 64);
    const u16* qc = qb + (size_t)c0 * 1024;
    gemm_bt<0, 0><<<dim3(32, mt, 1), blk, 0, stream>>>(
        mk(qc, Gt, zgc, vc, 4096, 1024, 1024, 1024, 4096));
    {
      GA a = mk(qc, Vt, zgc, vc, 4096, 1024, 1024, 1024, 4096);
      a.E0[0] = zgc; a.lde0 = 4096;   // in-place: read zg then overwrite with h
      gemm_bt<4, 0><<<dim3(32, mt, 1), blk, 0, stream>>>(a);
    }
    gemm64<0><<<dim3(16, mt64, 1), blk, 0, stream>>>(
        mk(zgc, Pt, oc, vc, 1024, 4096, 4096, 4096, 1024));
    {
      GA a = mk(oc, projWt, out + (size_t)c0 * 1024, vc, 1024, 1024, 1024, 1024, 1024);
      a.E0[0] = proj_b;
      gemm64<6><<<dim3(16, mt64, 1), blk, 0, stream>>>(a);
    }
  }
}

// Round 5
// 6672.749 us; speedup vs baseline: 1.0876x; 1.0086x over previous
//
#include <hip/hip_runtime.h>
#include <stdint.h>

#define NTOK 10992      // B*SN
#define NTOKA 11264     // padded token dim
#define FCHK 5632       // final-forward chunk
#define PMi 4194304

typedef unsigned short u16;
typedef __attribute__((ext_vector_type(8))) __bf16 b8;
typedef __attribute__((ext_vector_type(4))) float f32x4;

__device__ __forceinline__ u16 f2b(float f) {
  union { float f; uint32_t u; } v; v.f = f;
  return (u16)((v.u + 0x7fffu + ((v.u >> 16) & 1u)) >> 16);   // RNE
}
__device__ __forceinline__ float b2f(u16 b) {
  union { uint32_t u; float f; } v; v.u = ((uint32_t)b) << 16; return v.f;
}
__device__ __forceinline__ uint2 pk4(u16 a, u16 b, u16 c, u16 d) {
  uint2 r; r.x = (uint32_t)a | ((uint32_t)b << 16); r.y = (uint32_t)c | ((uint32_t)d << 16);
  return r;
}
__device__ __forceinline__ void gload16(const u16* g, u16* l) {
  __builtin_amdgcn_global_load_lds((const __attribute__((address_space(1))) void*)(const void*)g,
                                   (__attribute__((address_space(3))) void*)(void*)l, 16, 0, 0);
}

struct GA {
  const u16* A[3]; const u16* B[3];
  void* C[3]; u16* O1[3]; u16* OT[3];
  const void* E0[3]; const u16* E1[3];
  int lda[3], ldb[3];
  int M, N, K, ldc, ldo1, ldt, lde0, lde1;
  float p0, p1;
};

// ---------------- 128x128 tile GEMM: C[m,n] = sum_k A[m,k]*B[n,k] ----------------
// EPI: 0 Cb=acc | 1 Cb=acc+E0f[n] | 3 Cb=acc(zv), h=swish(E0b)*acc -> O1 + OT(T-pack)
//      4 Cb=swish(E0b)*acc (in-place ok) | 5 dzg->C(T-pack), dzv->O1(T-pack)
//      6 Cf=acc+E0f[n] | 8 atomicAdd(Cf, acc) | 9 Cb=p0*E0b+acc, + OT(T-pack)
template <int EPI, int SPLIT>
__global__ __launch_bounds__(256, 2) void gemm_bt(GA g) {
  __shared__ u16 As[128 * 32];
  __shared__ u16 Bs[128 * 32];
  int bz = blockIdx.z, koff = 0, klen = g.K;
  if constexpr (SPLIT) { koff = (bz & 1) * (g.K >> 1); bz >>= 1; klen = g.K >> 1; }
  const u16* __restrict__ A = g.A[bz] + koff;
  const u16* __restrict__ B = g.B[bz] + koff;
  const int lda = g.lda[bz], ldb = g.ldb[bz];
  const int m0 = blockIdx.y * 128, n0 = blockIdx.x * 128;
  const int tid = threadIdx.x, w = tid >> 6, lane = tid & 63;
  const int wr = (w >> 1) * 64, wc = (w & 1) * 64;
  const int ln = lane & 15, lq = lane >> 4;

  f32x4 acc[4][4];
#pragma unroll
  for (int i = 0; i < 4; ++i)
#pragma unroll
    for (int j = 0; j < 4; ++j)
#pragma unroll
      for (int r = 0; r < 4; ++r) acc[i][j][r] = 0.f;

  const u16* Ag = A + (size_t)(m0 + 32 * w + (lane >> 2)) * lda + (lane & 3) * 8;
  const u16* Bg = B + (size_t)(n0 + 32 * w + (lane >> 2)) * ldb + (lane & 3) * 8;
  u16* AsW = &As[w * 1024];
  u16* BsW = &Bs[w * 1024];
  const int nkt = klen >> 5;

  for (int kt = 0; kt < nkt; ++kt) {
    __syncthreads();
    gload16(Ag, AsW);
    gload16(Ag + (size_t)16 * lda, AsW + 512);
    gload16(Bg, BsW);
    gload16(Bg + (size_t)16 * ldb, BsW + 512);
    Ag += 32; Bg += 32;
    __syncthreads();
    b8 af[4], bfr[4];
#pragma unroll
    for (int i = 0; i < 4; ++i) af[i] = *(const b8*)&As[(wr + i * 16 + ln) * 32 + lq * 8];
#pragma unroll
    for (int j = 0; j < 4; ++j) bfr[j] = *(const b8*)&Bs[(wc + j * 16 + ln) * 32 + lq * 8];
#pragma unroll
    for (int i = 0; i < 4; ++i)
#pragma unroll
      for (int j = 0; j < 4; ++j)
        acc[i][j] = __builtin_amdgcn_mfma_f32_16x16x32_bf16(af[i], bfr[j], acc[i][j], 0, 0, 0);
  }

  float* Cf = (float*)g.C[bz];
  u16* Cb = (u16*)g.C[bz];
  u16* O1 = g.O1[bz];
  u16* OT = g.OT[bz];
  const float* E0f = (const float*)g.E0[bz];
  const u16* E0b = (const u16*)g.E0[bz];
  const u16* E1b = g.E1[bz];

#pragma unroll
  for (int i = 0; i < 4; ++i) {
    const int mb = m0 + wr + i * 16 + lq * 4;
    if (mb >= g.M) continue;
#pragma unroll
    for (int j = 0; j < 4; ++j) {
      const int n = n0 + wc + j * 16 + ln;
      if (n >= g.N) continue;
      float vv[4];
#pragma unroll
      for (int r = 0; r < 4; ++r) vv[r] = acc[i][j][r];
      if constexpr (EPI == 0) {
#pragma unroll
        for (int r = 0; r < 4; ++r) Cb[(size_t)(mb + r) * g.ldc + n] = f2b(vv[r]);
      } else if constexpr (EPI == 1) {
        const float bias = E0f[n];
#pragma unroll
        for (int r = 0; r < 4; ++r) Cb[(size_t)(mb + r) * g.ldc + n] = f2b(vv[r] + bias);
      } else if constexpr (EPI == 3) {
        u16 oq[4];
#pragma unroll
        for (int r = 0; r < 4; ++r) {
          const int m = mb + r;
          Cb[(size_t)m * g.ldc + n] = f2b(vv[r]);
          const float zg = b2f(E0b[(size_t)m * g.lde0 + n]);
          const float s = 1.f / (1.f + __expf(-zg));
          const u16 ub = f2b(zg * s * vv[r]);
          O1[(size_t)m * g.ldo1 + n] = ub;
          oq[r] = ub;
        }
        *(uint2*)&OT[(size_t)n * g.ldt + mb] = pk4(oq[0], oq[1], oq[2], oq[3]);
      } else if constexpr (EPI == 4) {
#pragma unroll
        for (int r = 0; r < 4; ++r) {
          const int m = mb + r;
          const float zg = b2f(E0b[(size_t)m * g.lde0 + n]);
          const float s = 1.f / (1.f + __expf(-zg));
          Cb[(size_t)m * g.ldc + n] = f2b(zg * s * vv[r]);
        }
      } else if constexpr (EPI == 5) {
        u16 cq[4], oq[4];
#pragma unroll
        for (int r = 0; r < 4; ++r) {
          const int m = mb + r;
          const float zg = b2f(E0b[(size_t)m * g.lde0 + n]);
          const float zv = b2f(E1b[(size_t)m * g.lde1 + n]);
          const float s = 1.f / (1.f + __expf(-zg));
          cq[r] = f2b(vv[r] * zv * s * (1.f + zg * (1.f - s)));
          oq[r] = f2b(vv[r] * zg * s);
        }
        *(uint2*)&Cb[(size_t)n * g.ldt + mb] = pk4(cq[0], cq[1], cq[2], cq[3]);
        *(uint2*)&O1[(size_t)n * g.ldt + mb] = pk4(oq[0], oq[1], oq[2], oq[3]);
      } else if constexpr (EPI == 6) {
        const float bias = E0f[n];
#pragma unroll
        for (int r = 0; r < 4; ++r) Cf[(size_t)(mb + r) * g.ldc + n] = vv[r] + bias;
      } else if constexpr (EPI == 8) {
#pragma unroll
        for (int r = 0; r < 4; ++r) atomicAdd(&Cf[(size_t)(mb + r) * g.ldc + n], vv[r]);
      } else if constexpr (EPI == 9) {
        u16 cq[4];
#pragma unroll
        for (int r = 0; r < 4; ++r) {
          const int m = mb + r;
          const u16 ub = f2b(g.p0 * b2f(E0b[(size_t)m * g.lde0 + n]) + vv[r]);
          Cb[(size_t)m * g.ldc + n] = ub;
          cq[r] = ub;
        }
        *(uint2*)&OT[(size_t)n * g.ldt + mb] = pk4(cq[0], cq[1], cq[2], cq[3]);
      }
    }
  }
}

// ---------------- 64x64 tile GEMM (for small-N shapes) ----------------
// EPI: 0 Cb=acc | 2 v=(acc-E0b)*p0 -> Cb + OT(T-pack) | 6 Cf=acc+E0f[n] | 7 Cb=p0*E0b+p1*acc
template <int EPI>
__global__ __launch_bounds__(256, 2) void gemm64(GA g) {
  __shared__ u16 As[64 * 32];
  __shared__ u16 Bs[64 * 32];
  const int bz = blockIdx.z;
  const u16* __restrict__ A = g.A[bz];
  const u16* __restrict__ B = g.B[bz];
  const int lda = g.lda[bz], ldb = g.ldb[bz];
  const int m0 = blockIdx.y * 64, n0 = blockIdx.x * 64;
  const int tid = threadIdx.x, w = tid >> 6, lane = tid & 63;
  const int wr = (w >> 1) * 32, wc = (w & 1) * 32;
  const int ln = lane & 15, lq = lane >> 4;

  f32x4 acc[2][2];
#pragma unroll
  for (int i = 0; i < 2; ++i)
#pragma unroll
    for (int j = 0; j < 2; ++j)
#pragma unroll
      for (int r = 0; r < 4; ++r) acc[i][j][r] = 0.f;

  const u16* Ag = A + (size_t)(m0 + 16 * w + (lane >> 2)) * lda + (lane & 3) * 8;
  const u16* Bg = B + (size_t)(n0 + 16 * w + (lane >> 2)) * ldb + (lane & 3) * 8;
  u16* AsW = &As[w * 512];
  u16* BsW = &Bs[w * 512];
  const int nkt = g.K >> 5;

  for (int kt = 0; kt < nkt; ++kt) {
    __syncthreads();
    gload16(Ag, AsW);
    gload16(Bg, BsW);
    Ag += 32; Bg += 32;
    __syncthreads();
    b8 af[2], bfr[2];
#pragma unroll
    for (int i = 0; i < 2; ++i) af[i] = *(const b8*)&As[(wr + i * 16 + ln) * 32 + lq * 8];
#pragma unroll
    for (int j = 0; j < 2; ++j) bfr[j] = *(const b8*)&Bs[(wc + j * 16 + ln) * 32 + lq * 8];
#pragma unroll
    for (int i = 0; i < 2; ++i)
#pragma unroll
      for (int j = 0; j < 2; ++j)
        acc[i][j] = __builtin_amdgcn_mfma_f32_16x16x32_bf16(af[i], bfr[j], acc[i][j], 0, 0, 0);
  }

  float* Cf = (float*)g.C[bz];
  u16* Cb = (u16*)g.C[bz];
  u16* OT = g.OT[bz];
  const float* E0f = (const float*)g.E0[bz];
  const u16* E0b = (const u16*)g.E0[bz];

#pragma unroll
  for (int i = 0; i < 2; ++i) {
    const int mb = m0 + wr + i * 16 + lq * 4;
    if (mb >= g.M) continue;
#pragma unroll
    for (int j = 0; j < 2; ++j) {
      const int n = n0 + wc + j * 16 + ln;
      if (n >= g.N) continue;
      float vv[4];
#pragma unroll
      for (int r = 0; r < 4; ++r) vv[r] = acc[i][j][r];
      if constexpr (EPI == 0) {
#pragma unroll
        for (int r = 0; r < 4; ++r) Cb[(size_t)(mb + r) * g.ldc + n] = f2b(vv[r]);
      } else if constexpr (EPI == 2) {
        u16 cq[4];
#pragma unroll
        for (int r = 0; r < 4; ++r) {
          const int m = mb + r;
          const u16 ub = f2b((vv[r] - b2f(E0b[(size_t)m * g.lde0 + n])) * g.p0);
          Cb[(size_t)m * g.ldc + n] = ub;
          cq[r] = ub;
        }
        *(uint2*)&OT[(size_t)n * g.ldt + mb] = pk4(cq[0], cq[1], cq[2], cq[3]);
      } else if constexpr (EPI == 6) {
        const float bias = E0f[n];
#pragma unroll
        for (int r = 0; r < 4; ++r) Cf[(size_t)(mb + r) * g.ldc + n] = vv[r] + bias;
      } else if constexpr (EPI == 7) {
#pragma unroll
        for (int r = 0; r < 4; ++r) {
          const int m = mb + r;
          Cb[(size_t)m * g.ldc + n] =
              f2b(g.p0 * b2f(E0b[(size_t)m * g.lde0 + n]) + g.p1 * vv[r]);
        }
      }
    }
  }
}

__global__ __launch_bounds__(256) void norm_qkv(const u16* __restrict__ qkvB,
    const float* __restrict__ qs, const float* __restrict__ qbi,
    const float* __restrict__ ks, const float* __restrict__ kbi,
    u16* __restrict__ qb, u16* __restrict__ kb, u16* __restrict__ vb) {
  const int tok = blockIdx.x;
  const int t = threadIdx.x;
  const int d = t * 4;
  const u16* row = qkvB + (size_t)tok * 3072;
  const uint2 qu = *(const uint2*)(row + d);
  const uint2 ku = *(const uint2*)(row + 1024 + d);
  *(uint2*)(vb + (size_t)tok * 1024 + d) = *(const uint2*)(row + 2048 + d);
  float q0 = b2f(qu.x & 0xffff), q1 = b2f(qu.x >> 16), q2 = b2f(qu.y & 0xffff), q3 = b2f(qu.y >> 16);
  float k0 = b2f(ku.x & 0xffff), k1 = b2f(ku.x >> 16), k2 = b2f(ku.y & 0xffff), k3 = b2f(ku.y >> 16);
  float sq = q0 * q0 + q1 * q1 + q2 * q2 + q3 * q3;
  float sk = k0 * k0 + k1 * k1 + k2 * k2 + k3 * k3;
  for (int off = 1; off < 16; off <<= 1) { sq += __shfl_xor(sq, off); sk += __shfl_xor(sk, off); }
  const float rq = 1.f / (sqrtf(sq) + 1e-6f);
  const float rk = 1.f / (sqrtf(sk) + 1e-6f);
  const int hd = d & 63;
  const float4 qsv = *(const float4*)(qs + hd);
  const float4 qbv = *(const float4*)(qbi + hd);
  const float4 ksv = *(const float4*)(ks + hd);
  const float4 kbv = *(const float4*)(kbi + hd);
  uint64_t pq = (uint64_t)f2b(q0 * rq * qsv.x + qbv.x)
              | ((uint64_t)f2b(q1 * rq * qsv.y + qbv.y) << 16)
              | ((uint64_t)f2b(q2 * rq * qsv.z + qbv.z) << 32)
              | ((uint64_t)f2b(q3 * rq * qsv.w + qbv.w) << 48);
  uint64_t pk = (uint64_t)f2b(k0 * rk * ksv.x + kbv.x)
              | ((uint64_t)f2b(k1 * rk * ksv.y + kbv.y) << 16)
              | ((uint64_t)f2b(k2 * rk * ksv.z + kbv.z) << 32)
              | ((uint64_t)f2b(k3 * rk * ksv.w + kbv.w) << 48);
  *(uint64_t*)(qb + (size_t)tok * 1024 + d) = pq;
  *(uint64_t*)(kb + (size_t)tok * 1024 + d) = pk;
}

__global__ __launch_bounds__(256) void tr_b16(const u16* __restrict__ in, u16* __restrict__ out,
                                              int Cin, int Rtot, int Rval,
                                              size_t inStr, size_t outStr) {
  const int b = blockIdx.z;
  in += (size_t)b * inStr; out += (size_t)b * outStr;
  __shared__ u16 t[32][33];
  const int c0 = blockIdx.x * 32, r0 = blockIdx.y * 32;
  const int tx = threadIdx.x, ty = threadIdx.y;
#pragma unroll
  for (int yy = 0; yy < 4; ++yy) {
    const int rr = ty * 4 + yy;
    const int r = r0 + rr;
    t[rr][tx] = (r < Rval) ? in[(size_t)r * Cin + c0 + tx] : (u16)0;
  }
  __syncthreads();
#pragma unroll
  for (int yy = 0; yy < 4; ++yy) {
    const int cc = ty * 4 + yy;
    out[(size_t)(c0 + cc) * Rtot + r0 + tx] = t[tx][cc];
  }
}

__global__ __launch_bounds__(256) void tr_f32b(const float* __restrict__ in, u16* __restrict__ out,
                                               int Cin, int Rtot) {
  __shared__ u16 t[32][33];
  const int c0 = blockIdx.x * 32, r0 = blockIdx.y * 32;
  const int tx = threadIdx.x, ty = threadIdx.y;
#pragma unroll
  for (int yy = 0; yy < 4; ++yy) {
    const int rr = ty * 4 + yy;
    t[rr][tx] = f2b(in[(size_t)(r0 + rr) * Cin + c0 + tx]);
  }
  __syncthreads();
#pragma unroll
  for (int yy = 0; yy < 4; ++yy) {
    const int cc = ty * 4 + yy;
    out[(size_t)(c0 + cc) * Rtot + r0 + tx] = t[tx][cc];
  }
}

__global__ void cvt_k(const float* __restrict__ in, u16* __restrict__ out, int n) {
  const int i = blockIdx.x * 256 + threadIdx.x;
  if (i < n) out[i] = f2b(in[i]);
}

__global__ void diag_k(float* __restrict__ out, int n, float val) {
  const int i = blockIdx.x * 256 + threadIdx.x;
  if (i < n) out[i] = val;
}

__global__ __launch_bounds__(256) void sumsq_k(const float* __restrict__ g, float* __restrict__ out) {
  const int b = blockIdx.y;
  const float* p = g + (size_t)b * PMi;
  float s = 0.f;
  for (int i = blockIdx.x * 256 + threadIdx.x; i < PMi; i += gridDim.x * 256) {
    float v = p[i]; s += v * v;
  }
  for (int off = 32; off > 0; off >>= 1) s += __shfl_xor(s, off);
  __shared__ float red[4];
  if ((threadIdx.x & 63) == 0) red[threadIdx.x >> 6] = s;
  __syncthreads();
  if (threadIdx.x == 0) atomicAdd(out + b, red[0] + red[1] + red[2] + red[3]);
}

__global__ __launch_bounds__(256) void scale_k(const float* __restrict__ g, const float* __restrict__ ss,
                                               u16* __restrict__ Xb) {
  const int b = blockIdx.y;
  const float r = 1.f / (sqrtf(ss[b]) + 1e-7f);
  const size_t o = (size_t)b * PMi;
  for (int i = blockIdx.x * 256 + threadIdx.x; i < PMi; i += gridDim.x * 256)
    Xb[o + i] = f2b(g[o + i] * r);
}

__global__ __launch_bounds__(256) void muon_apply(const u16* __restrict__ Xb_,
    u16* __restrict__ Gt, u16* __restrict__ Vt, u16* __restrict__ Pt, u16* __restrict__ Pb) {
  const int b = blockIdx.z;
  __shared__ float xs[32][33];
  __shared__ u16 ns[32][33];
  const int j0 = blockIdx.x * 32;
  const int i0 = blockIdx.y * 32;
  const u16* X = Xb_ + (size_t)b * PMi;
  const int tx = threadIdx.x, ty = threadIdx.y;
#pragma unroll
  for (int yy = 0; yy < 4; ++yy) {
    const int r = ty * 4 + yy;
    xs[r][tx] = b2f(X[(size_t)(i0 + r) * 4096 + j0 + tx]);
  }
  __syncthreads();
  if (b < 2) {
    u16* T = b ? Vt : Gt;
#pragma unroll
    for (int yy = 0; yy < 4; ++yy) {
      const int rr = ty * 4 + yy;
      const size_t idx = (size_t)(j0 + rr) * 1024 + i0 + tx;
      T[idx] = f2b(b2f(T[idx]) - 0.1f * xs[tx][rr]);
    }
  } else {
#pragma unroll
    for (int yy = 0; yy < 4; ++yy) {
      const int rr = ty * 4 + yy;
      const size_t idx = (size_t)(j0 + rr) * 1024 + i0 + tx;
      const float nv = b2f(Pb[idx]) - 0.1f * xs[tx][rr];
      const u16 nb = f2b(nv);
      Pb[idx] = nb;
      ns[rr][tx] = nb;
    }
    __syncthreads();
#pragma unroll
    for (int yy = 0; yy < 4; ++yy) {
      const int rr = ty * 4 + yy;
      Pt[(size_t)(i0 + rr) * 4096 + j0 + tx] = ns[tx][rr];
    }
  }
}

static GA mk(const u16* A, const u16* B, void* C, int M, int N, int K,
             int lda, int ldb, int ldc) {
  GA a{};
  a.A[0] = a.A[1] = a.A[2] = A;
  a.B[0] = a.B[1] = a.B[2] = B;
  a.C[0] = a.C[1] = a.C[2] = C;
  a.lda[0] = a.lda[1] = a.lda[2] = lda;
  a.ldb[0] = a.ldb[1] = a.ldb[2] = ldb;
  a.M = M; a.N = N; a.K = K; a.ldc = ldc;
  return a;
}

extern "C" void kernel_launch(void* const* d_in, const int* in_sizes, int n_in,
                              void* d_out, int out_size, void* d_ws, size_t ws_size,
                              hipStream_t stream) {
  (void)in_sizes; (void)n_in;
  const float* x      = (const float*)d_in[0];
  const float* qkv_w  = (const float*)d_in[1];
  const float* qkv_b  = (const float*)d_in[2];
  const float* qn_s   = (const float*)d_in[3];
  const float* qn_b   = (const float*)d_in[4];
  const float* kn_s   = (const float*)d_in[5];
  const float* kn_b   = (const float*)d_in[6];
  const float* g_gate = (const float*)d_in[7];
  const float* g_val  = (const float*)d_in[8];
  const float* g_proj = (const float*)d_in[9];
  const float* proj_w = (const float*)d_in[10];
  const float* proj_b = (const float*)d_in[11];
  float* out = (float*)d_out;

  const size_t PM = PMi;
  const size_t TD = (size_t)NTOKA * 1024;

  // persistent = 127,926,528 B. NCH=8 arena = 113,770,496 (fits round-3 NEED);
  // NCH=4 arena = 177,209,344 -> NEED2 = 305,135,872.
  const size_t NEED1 = 253231360 + 4096;
  const size_t NEED2 = 127926528 + 177209344 + 4096;
  if (ws_size < NEED1) {
    diag_k<<<dim3((out_size + 255) / 256), dim3(256), 0, stream>>>(out, out_size,
                                                                   (float)(ws_size >> 20));
    return;
  }
  const int CHKr = (ws_size >= NEED2) ? 2816 : 1408;   // runtime-adaptive chunk

  char* p = (char*)d_ws;
  auto carve = [&](size_t bytes) { char* r = p; p += (bytes + 255) & ~(size_t)255; return (void*)r; };
  auto cdiv = [](int a, int b) { return (a + b - 1) / b; };

  // ---- persistent (127.93 MB) ----
  u16* Gt     = (u16*)carve(PM * 2);         // G^T [4096,1024]
  u16* Vt     = (u16*)carve(PM * 2);         // V^T [4096,1024]
  u16* Pt     = (u16*)carve(PM * 2);         // P^T [1024,4096]
  u16* Pb     = (u16*)carve(PM * 2);         // P   [4096,1024]
  u16* projWt = (u16*)carve(1048576ull * 2);
  u16* qb     = (u16*)carve(TD * 2);
  u16* kb     = (u16*)carve(TD * 2);
  u16* vT     = (u16*)carve(TD * 2);         // v^T [1024, NTOKA]
  u16* kT     = (u16*)carve(TD * 2);
  float* ssq  = (float*)carve(256);
  char* arena = p;

  // P0 staging
  u16* xb     = (u16*)arena;
  u16* qkvWt  = (u16*)(arena + 23068672);
  u16* qkvB   = (u16*)(arena + 29360128);                     // NTOK x 3072
  u16* vb_tmp = (u16*)(arena + 96894976);
  // P1 backward per chunk (runtime CHKr): zg | zv | hh(->dzgT) | hT | dzvT | dpredT | dpredb | gAll
  const size_t CB = (size_t)CHKr * 4096 * 2;
  const size_t DP = (size_t)CHKr * 1024 * 2;
  u16* zg     = (u16*)arena;
  u16* zv     = (u16*)(arena + CB);
  u16* hh     = (u16*)(arena + 2 * CB);       // reused as dzgT after dpred
  u16* hT     = (u16*)(arena + 3 * CB);
  u16* dzvT   = (u16*)(arena + 4 * CB);
  u16* dpredT = (u16*)(arena + 5 * CB);
  u16* dpredb = (u16*)(arena + 5 * CB + DP);
  float* gAll = (float*)(arena + 5 * CB + 2 * DP);
  // P2 Newton-Schulz (113.25 MB, fits both layouts)
  u16* XAb  = (u16*)arena;
  u16* XAbT = (u16*)(arena + 25165824);
  u16* XBb  = (u16*)(arena + 50331648);
  u16* XBbT = (u16*)(arena + 75497472);
  u16* Ab   = (u16*)(arena + 100663296);
  u16* Wb   = (u16*)(arena + 106954752);
  // P4 final forward per chunk (FCHK=5632)
  u16* zgc = (u16*)arena;
  u16* oc  = (u16*)(arena + 46137344);

  const dim3 blk(256), tb32(32, 8);
  const float inv2 = 2.0f / (10992.0f * 1024.0f);
  const float nsa = 3.4445f, nsb = -4.7750f, nsc = 2.0315f;

  // ---- setup ----
  cvt_k<<<dim3(43968), blk, 0, stream>>>(x, xb, NTOK * 1024);
  cvt_k<<<dim3(16384), blk, 0, stream>>>(g_proj, Pb, (int)PM);
  tr_f32b<<<dim3(96, 32), tb32, 0, stream>>>(qkv_w, qkvWt, 3072, 1024);
  tr_f32b<<<dim3(32, 32), tb32, 0, stream>>>(proj_w, projWt, 1024, 1024);
  tr_f32b<<<dim3(128, 32), tb32, 0, stream>>>(g_gate, Gt, 4096, 1024);
  tr_f32b<<<dim3(128, 32), tb32, 0, stream>>>(g_val, Vt, 4096, 1024);
  tr_f32b<<<dim3(32, 128), tb32, 0, stream>>>(g_proj, Pt, 1024, 4096);

  {
    GA a = mk(xb, qkvWt, qkvB, NTOK, 3072, 1024, 1024, 1024, 3072);
    a.E0[0] = a.E0[1] = a.E0[2] = qkv_b;
    gemm_bt<1, 0><<<dim3(24, 86, 1), blk, 0, stream>>>(a);
  }
  norm_qkv<<<dim3(NTOK), blk, 0, stream>>>(qkvB, qn_s, qn_b, kn_s, kn_b, qb, kb, vb_tmp);
  tr_b16<<<dim3(32, 352, 1), tb32, 0, stream>>>(kb, kT, 1024, NTOKA, NTOK, 0, 0);
  tr_b16<<<dim3(32, 352, 1), tb32, 0, stream>>>(vb_tmp, vT, 1024, NTOKA, NTOK, 0, 0);

  // ---- 2 TTT steps ----
  for (int step = 0; step < 2; ++step) {
    hipMemsetAsync(gAll, 0, 3 * PM * 4, stream);
    for (int c0 = 0; c0 < NTOK; c0 += CHKr) {
      const int vc = (NTOK - c0 < CHKr) ? (NTOK - c0) : CHKr;
      const int mt = cdiv(vc, 128);
      const u16* kc = kb + (size_t)c0 * 1024;
      if (vc < CHKr)  // tail chunk: zero hT|dzvT|dpredT before producers
        hipMemsetAsync(hT, 0, 2 * CB + DP, stream);
      // zg = k@G
      gemm_bt<0, 0><<<dim3(32, mt, 1), blk, 0, stream>>>(
          mk(kc, Gt, zg, vc, 4096, 1024, 1024, 1024, 4096));
      // zv = k@V ; h = swish(zg)*zv -> hh + hT
      {
        GA a = mk(kc, Vt, zv, vc, 4096, 1024, 1024, 1024, 4096);
        a.O1[0] = hh; a.ldo1 = 4096; a.OT[0] = hT; a.ldt = CHKr;
        a.E0[0] = zg; a.lde0 = 4096;
        gemm_bt<3, 0><<<dim3(32, mt, 1), blk, 0, stream>>>(a);
      }
      // dpredT[d,t] = (Pt@h^T - vT)*inv2 -> dpredT + dpredb(T-pack)
      {
        GA a = mk(Pt, hh, dpredT, 1024, vc, 4096, 4096, 4096, CHKr);
        a.OT[0] = dpredb; a.ldt = 1024;
        a.E0[0] = vT + c0; a.lde0 = NTOKA; a.p0 = inv2;
        gemm64<2><<<dim3(cdiv(vc, 64), 16, 1), blk, 0, stream>>>(a);
      }
      if (vc < CHKr)  // hh becomes dzgT: zero its token-tail before dz writes
        hipMemsetAsync(hh, 0, CB, stream);
      // dh = dpred@P^T -> dzgT(into hh), dzvT (T-packed)
      {
        GA a = mk(dpredb, Pb, hh, vc, 4096, 1024, 1024, 1024, 0);
        a.O1[0] = dzvT; a.ldt = CHKr;
        a.E0[0] = zg; a.lde0 = 4096; a.E1[0] = zv; a.lde1 = 4096;
        gemm_bt<5, 0><<<dim3(32, mt, 1), blk, 0, stream>>>(a);
      }
      // grads (split-K=2, atomic): gG=kT@dzgT, gV=kT@dzvT, gP^T=dpredT@hT
      {
        GA a{};
        a.A[0] = kT + c0; a.A[1] = kT + c0; a.A[2] = dpredT;
        a.lda[0] = NTOKA; a.lda[1] = NTOKA; a.lda[2] = CHKr;
        a.B[0] = hh; a.B[1] = dzvT; a.B[2] = hT;
        a.ldb[0] = a.ldb[1] = a.ldb[2] = CHKr;
        a.C[0] = gAll; a.C[1] = gAll + PM; a.C[2] = gAll + 2 * PM;
        a.M = 1024; a.N = 4096; a.K = CHKr; a.ldc = 4096;
        gemm_bt<8, 1><<<dim3(32, 8, 6), blk, 0, stream>>>(a);
      }
    }
    // X0 = g/||g||_F
    hipMemsetAsync(ssq, 0, 16, stream);
    sumsq_k<<<dim3(512, 3), blk, 0, stream>>>(gAll, ssq);
    scale_k<<<dim3(2048, 3), blk, 0, stream>>>(gAll, ssq, XAb);
    tr_b16<<<dim3(128, 32, 3), tb32, 0, stream>>>(XAb, XAbT, 4096, 1024, 1024, PM, PM);

    // Newton-Schulz x5, batched z=3
    u16* Xi_b = XAb; u16* Xi_bT = XAbT;
    u16* Xo_b = XBb; u16* Xo_bT = XBbT;
    for (int it = 0; it < 5; ++it) {
      {  // Ab = X@X^T (64-tile, grid 768)
        GA a{};
        for (int b = 0; b < 3; ++b) {
          a.A[b] = Xi_b + (size_t)b * PM; a.B[b] = Xi_b + (size_t)b * PM;
          a.C[b] = Ab + (size_t)b * 1048576;
          a.lda[b] = 4096; a.ldb[b] = 4096;
        }
        a.M = 1024; a.N = 1024; a.K = 4096; a.ldc = 1024;
        gemm64<0><<<dim3(16, 16, 3), blk, 0, stream>>>(a);
      }
      {  // W = nsb*A + nsc*A@A (64-tile)
        GA a{};
        for (int b = 0; b < 3; ++b) {
          a.A[b] = Ab + (size_t)b * 1048576; a.B[b] = Ab + (size_t)b * 1048576;
          a.C[b] = Wb + (size_t)b * 1048576; a.E0[b] = Ab + (size_t)b * 1048576;
          a.lda[b] = 1024; a.ldb[b] = 1024;
        }
        a.M = 1024; a.N = 1024; a.K = 1024; a.ldc = 1024; a.lde0 = 1024;
        a.p0 = nsb; a.p1 = nsc;
        gemm64<7><<<dim3(16, 16, 3), blk, 0, stream>>>(a);
      }
      {  // Xn = nsa*X + W@X -> Xo_b + Xo_bT (dual store)
        GA a{};
        for (int b = 0; b < 3; ++b) {
          a.A[b] = Wb + (size_t)b * 1048576; a.B[b] = Xi_bT + (size_t)b * PM;
          a.C[b] = Xo_b + (size_t)b * PM; a.OT[b] = Xo_bT + (size_t)b * PM;
          a.E0[b] = Xi_b + (size_t)b * PM;
          a.lda[b] = 1024; a.ldb[b] = 1024;
        }
        a.M = 1024; a.N = 4096; a.K = 1024; a.ldc = 4096; a.ldt = 1024;
        a.lde0 = 4096; a.p0 = nsa;
        gemm_bt<9, 0><<<dim3(32, 8, 3), blk, 0, stream>>>(a);
      }
      u16* tb = Xi_b; Xi_b = Xo_b; Xo_b = tb;
      u16* tt = Xi_bT; Xi_bT = Xo_bT; Xo_bT = tt;
    }
    muon_apply<<<dim3(128, 32, 3), tb32, 0, stream>>>(Xi_b, Gt, Vt, Pt, Pb);
  }

  // ---- final forward with q (2 chunks, h in-place over zg) ----
  for (int fc = 0; fc < 2; ++fc) {
    const int c0 = fc * FCHK;
    const int vc = (NTOK - c0 < FCHK) ? (NTOK - c0) : FCHK;
    const int mt = cdiv(vc, 128), mt64 = cdiv(vc, 64);
    const u16* qc = qb + (size_t)c0 * 1024;
    gemm_bt<0, 0><<<dim3(32, mt, 1), blk, 0, stream>>>(
        mk(qc, Gt, zgc, vc, 4096, 1024, 1024, 1024, 4096));
    {
      GA a = mk(qc, Vt, zgc, vc, 4096, 1024, 1024, 1024, 4096);
      a.E0[0] = zgc; a.lde0 = 4096;   // in-place: read zg then overwrite with h
      gemm_bt<4, 0><<<dim3(32, mt, 1), blk, 0, stream>>>(a);
    }
    gemm64<0><<<dim3(16, mt64, 1), blk, 0, stream>>>(
        mk(zgc, Pt, oc, vc, 1024, 4096, 4096, 4096, 1024));
    {
      GA a = mk(oc, projWt, out + (size_t)c0 * 1024, vc, 1024, 1024, 1024, 1024, 1024);
      a.E0[0] = proj_b;
      gemm64<6><<<dim3(16, mt64, 1), blk, 0, stream>>>(a);
    }
  }
}